// Round 3
// baseline (3163.315 us; speedup 1.0000x reference)
//
#include <hip/hip_runtime.h>

typedef __bf16 bf16x8 __attribute__((ext_vector_type(8)));
typedef float f32x4 __attribute__((ext_vector_type(4)));
typedef unsigned short u16;
typedef unsigned int u32;

// ---------------- helpers ----------------
__device__ __forceinline__ u16 f2b(float f) {
    union { float f; u32 u; } v; v.f = f;
    u32 r = v.u + 0x7fffu + ((v.u >> 16) & 1u);
    return (u16)(r >> 16);
}
__device__ __forceinline__ float b2f(u16 u) {
    union { u32 u; float f; } v; v.u = ((u32)u) << 16; return v.f;
}
__device__ __forceinline__ void gl_lds16(const u16* g, u16* l) {
    __builtin_amdgcn_global_load_lds(
        (const __attribute__((address_space(1))) void*)g,
        (__attribute__((address_space(3))) void*)l, 16, 0, 0);
}

// ---------------- LN (+shift+window-partition) ----------------
__global__ __launch_bounds__(256) void ln_kernel(
    const float* __restrict__ h, u16* __restrict__ out,
    const float* __restrict__ g, const float* __restrict__ bb,
    int D, int dsh, int shifted, int mode)
{
    const int lane = threadIdx.x & 63;
    const int t = blockIdx.x * 4 + (threadIdx.x >> 6);
    const float4 xv = *(const float4*)(h + (size_t)t * 256 + lane * 4);
    float s = xv.x + xv.y + xv.z + xv.w;
    float s2 = xv.x*xv.x + xv.y*xv.y + xv.z*xv.z + xv.w*xv.w;
    #pragma unroll
    for (int o = 32; o > 0; o >>= 1) { s += __shfl_xor(s, o); s2 += __shfl_xor(s2, o); }
    const float mu = s * 0.00390625f;
    const float var = s2 * 0.00390625f - mu * mu;
    const float rs = 1.0f / sqrtf(var + 1e-5f);
    const int c0 = lane * 4;
    const float4 gv = *(const float4*)(g + c0);
    const float4 bv = *(const float4*)(bb + c0);
    ushort4 o4;
    o4.x = f2b((xv.x - mu) * rs * gv.x + bv.x);
    o4.y = f2b((xv.y - mu) * rs * gv.y + bv.y);
    o4.z = f2b((xv.z - mu) * rs * gv.z + bv.z);
    o4.w = f2b((xv.w - mu) * rs * gv.w + bv.w);
    size_t oidx;
    if (mode == 1) {
        oidx = (size_t)t * 256 + c0;
    } else {
        const int b = t >> (dsh + 12);
        const int rem = t & ((1 << (dsh + 12)) - 1);
        int d = rem >> 12;
        const int l = rem & 4095;
        int hh = l >> 6, ww = l & 63;
        if (shifted) { d = d ? d - 1 : D - 1; hh = (hh - 4) & 63; ww = (ww - 4) & 63; }
        const int widx = (b << (dsh + 5)) + ((d >> 1) << 6) + ((hh >> 3) << 3) + (ww >> 3);
        const int n = ((d & 1) << 6) + ((hh & 7) << 3) + (ww & 7);
        oidx = ((size_t)(widx * 128 + n)) * 256 + c0;
    }
    *(ushort4*)(out + oidx) = o4;
}

// ---------------- fp32 -> bf16 cast ----------------
__global__ __launch_bounds__(256) void cast_kernel(const float* __restrict__ in, u16* __restrict__ out, int n4)
{
    const int i = blockIdx.x * 256 + threadIdx.x;
    if (i >= n4) return;
    const float4 v = ((const float4*)in)[i];
    ushort4 o; o.x = f2b(v.x); o.y = f2b(v.y); o.z = f2b(v.z); o.w = f2b(v.w);
    ((ushort4*)out)[i] = o;
}

// ---------------- weight transpose+cast ----------------
__global__ __launch_bounds__(256) void wt_kernel(const float* __restrict__ src, u16* __restrict__ dst, int K, int N)
{
    const size_t base = (size_t)blockIdx.y * K * N;
    const int idx = blockIdx.x * 256 + threadIdx.x;
    const int k = idx / N, n = idx - k * N;
    dst[base + (size_t)n * K + k] = f2b(src[base + idx]);
}

// ---------------- MFMA bf16 GEMM, 128x128 tile ----------------
// Staging: global_load_lds width=16 into unpadded [128][32] K-panels with
// XOR-swizzled 16B slots (slot_lds = slot_glob ^ (row&3)) to tame ds_read_b128
// bank conflicts. Epilogue: 32-row LDS-transpose chunks -> contiguous 256/512B
// row-segment global writes (and matching coalesced hin reads for residual).
struct GemmP {
    const u16* A; const u16* Bt;
    int K;
    const float* bias;
    u16* outb;
    float* outf;
    const float* hin; float* hout;
    int D, shifted, nwsh, row_off;
};

template <int EPI>
__global__ __launch_bounds__(256, 2) void gemm_kernel(GemmP p)
{
    __shared__ __align__(16) char smem[16896];  // As 8KB | Bs 8KB ; CF 32x132 f32 overlay
    u16* As = (u16*)smem;
    u16* Bs = (u16*)(smem + 8192);
    float* CF = (float*)smem;

    const int tid = threadIdx.x;
    const int m0 = blockIdx.x * 128, n0 = blockIdx.y * 128;
    const int K = p.K;
    const int lane = tid & 63;
    const int wv = tid >> 6;
    const int wm = (wv & 1) * 64, wn = (wv >> 1) * 64;
    const int l16 = lane & 15, quad = lane >> 4;

    f32x4 acc[4][4];
    #pragma unroll
    for (int a = 0; a < 4; a++)
        #pragma unroll
        for (int b = 0; b < 4; b++)
            acc[a][b] = f32x4{0.f, 0.f, 0.f, 0.f};

    // staging: wave wv, instr j in {0,1}: rows rA0 + j*64 .. +15; lane covers
    // row rA0 + j*64 + (lane>>2), global 16B slot (lane&3)^(lrow&3)
    const int lrow = lane >> 2;
    const int c16s = (lane & 3) ^ (lrow & 3);
    const int rA0 = wv * 16;
    const u16* Ag = p.A + (size_t)(m0 + rA0 + lrow) * K + c16s * 8;
    const u16* Bg = p.Bt + (size_t)(n0 + rA0 + lrow) * K + c16s * 8;
    u16* Al = As + rA0 * 32;
    u16* Bl = Bs + rA0 * 32;
    const size_t j64 = (size_t)64 * K;
    const int fslot = (quad ^ (l16 & 3)) * 8;

    for (int k0 = 0; k0 < K; k0 += 32) {
        __syncthreads();
        gl_lds16(Ag + k0, Al);
        gl_lds16(Ag + j64 + k0, Al + 64 * 32);
        gl_lds16(Bg + k0, Bl);
        gl_lds16(Bg + j64 + k0, Bl + 64 * 32);
        __syncthreads();   // drains vmcnt(0) -> panels resident
        bf16x8 af[4], bfr[4];
        #pragma unroll
        for (int mt = 0; mt < 4; mt++) af[mt] = *(const bf16x8*)(As + (wm + mt * 16 + l16) * 32 + fslot);
        #pragma unroll
        for (int nt = 0; nt < 4; nt++) bfr[nt] = *(const bf16x8*)(Bs + (wn + nt * 16 + l16) * 32 + fslot);
        #pragma unroll
        for (int mt = 0; mt < 4; mt++)
            #pragma unroll
            for (int nt = 0; nt < 4; nt++)
                acc[mt][nt] = __builtin_amdgcn_mfma_f32_16x16x32_bf16(af[mt], bfr[nt], acc[mt][nt], 0, 0, 0);
    }

    // ---- transposed epilogue: 4 chunks of 32 rows ----
    const int crow = tid >> 3;        // 0..31
    const int ccol = (tid & 7) * 16;  // 0..112
    #pragma unroll
    for (int c = 0; c < 4; c++) {
        __syncthreads();
        if ((wv & 1) == (c >> 1)) {
            const int mt0 = (c & 1) * 2;
            #pragma unroll
            for (int mt2 = 0; mt2 < 2; mt2++)
                #pragma unroll
                for (int nt = 0; nt < 4; nt++)
                    #pragma unroll
                    for (int i = 0; i < 4; i++)
                        CF[(mt2 * 16 + quad * 4 + i) * 132 + wn + nt * 16 + l16] = acc[mt0 + mt2][nt][i];
        }
        __syncthreads();
        const int rowg = m0 + c * 32 + crow;
        const int colg = n0 + ccol;
        float v[16];
        #pragma unroll
        for (int j = 0; j < 16; j += 4) {
            const float4 t = *(const float4*)(CF + crow * 132 + ccol + j);
            v[j] = t.x; v[j+1] = t.y; v[j+2] = t.z; v[j+3] = t.w;
        }
        if constexpr (EPI == 0) { // qkv: +bias, q-scale, bf16 stride 768
            union { u16 s[16]; uint4 q[2]; } pk;
            #pragma unroll
            for (int j = 0; j < 16; j++) {
                float t = v[j] + p.bias[colg + j];
                if (colg + j < 256) t *= 0.125f;
                pk.s[j] = f2b(t);
            }
            u16* op = p.outb + (size_t)rowg * 768 + colg;
            *(uint4*)op = pk.q[0];
            *(uint4*)(op + 8) = pk.q[1];
        } else if constexpr (EPI == 1) { // proj: +bias, window-reverse, residual
            const int widx = rowg >> 7, n = rowg & 127;
            const int b = widx >> p.nwsh, rem = widx & ((1 << p.nwsh) - 1);
            int dd = ((rem >> 6) << 1) + (n >> 6);
            int hh = (((rem >> 3) & 7) << 3) + ((n >> 3) & 7);
            int ww = ((rem & 7) << 3) + (n & 7);
            if (p.shifted) { dd = (dd + 1 == p.D) ? 0 : dd + 1; hh = (hh + 4) & 63; ww = (ww + 4) & 63; }
            const size_t tok = (size_t)((b * p.D + dd) * 4096 + hh * 64 + ww);
            const float* hi = p.hin + tok * 256 + colg;
            float* ho = p.hout + tok * 256 + colg;
            #pragma unroll
            for (int j = 0; j < 16; j += 4) {
                const float4 r = *(const float4*)(hi + j);
                float4 o;
                o.x = r.x + v[j]   + p.bias[colg + j];
                o.y = r.y + v[j+1] + p.bias[colg + j + 1];
                o.z = r.z + v[j+2] + p.bias[colg + j + 2];
                o.w = r.w + v[j+3] + p.bias[colg + j + 3];
                *(float4*)(ho + j) = o;
            }
        } else if constexpr (EPI == 2) { // mlp1: +bias, exact gelu, bf16 stride 1024
            union { u16 s[16]; uint4 q[2]; } pk;
            #pragma unroll
            for (int j = 0; j < 16; j++) {
                float t = v[j] + p.bias[colg + j];
                t = 0.5f * t * (1.0f + erff(t * 0.7071067811865475f));
                pk.s[j] = f2b(t);
            }
            u16* op = p.outb + (size_t)rowg * 1024 + colg;
            *(uint4*)op = pk.q[0];
            *(uint4*)(op + 8) = pk.q[1];
        } else if constexpr (EPI == 3) { // mlp2: +bias, residual
            const size_t tok = (size_t)(p.row_off + rowg);
            const float* hi = p.hin + tok * 256 + colg;
            float* ho = p.hout + tok * 256 + colg;
            #pragma unroll
            for (int j = 0; j < 16; j += 4) {
                const float4 r = *(const float4*)(hi + j);
                float4 o;
                o.x = r.x + v[j]   + p.bias[colg + j];
                o.y = r.y + v[j+1] + p.bias[colg + j + 1];
                o.z = r.z + v[j+2] + p.bias[colg + j + 2];
                o.w = r.w + v[j+3] + p.bias[colg + j + 3];
                *(float4*)(ho + j) = o;
            }
        } else { // expand: plain fp32 stride 512
            float* op = p.outf + (size_t)rowg * 512 + colg;
            #pragma unroll
            for (int j = 0; j < 16; j += 4)
                *(float4*)(op + j) = float4{v[j], v[j+1], v[j+2], v[j+3]};
        }
    }
}

// ---------------- MFMA attention: one block per (window, head) ----------------
__global__ __launch_bounds__(256, 2) void attn_mfma_kernel(
    const u16* __restrict__ qkv, u16* __restrict__ att,
    const float* __restrict__ rpbp, int D, int shifted, int w0g, int nwsh)
{
    __shared__ __align__(16) char smem[57856];
    u16* Qs = (u16*)smem;                       // 128*72
    u16* Ks = (u16*)(smem + 18432);
    u16* Ps = (u16*)smem;                       // 128*136 overlays Qs+Ks
    u16* Vt = (u16*)(smem + 36864);             // 64*136
    float* rb = (float*)(smem + 54272);
    int* lbl = (int*)(smem + 56972);

    const int wloc = blockIdx.x;
    const int head = blockIdx.y;
    const int tid = threadIdx.x;
    const u16* base = qkv + (size_t)wloc * 98304;

    #pragma unroll
    for (int it = 0; it < 4; it++) {
        const int id = it * 256 + tid;
        const int row = id >> 3, oct = id & 7;
        const size_t ro = (size_t)row * 768 + head * 64 + oct * 8;
        *(uint4*)(Qs + row * 72 + oct * 8) = *(const uint4*)(base + ro);
        *(uint4*)(Ks + row * 72 + oct * 8) = *(const uint4*)(base + ro + 256);
        uint4 vv = *(const uint4*)(base + ro + 512);
        const u16* vp = (const u16*)&vv;
        #pragma unroll
        for (int q = 0; q < 8; q++) Vt[(oct * 8 + q) * 136 + row] = vp[q];
    }
    for (int j = tid; j < 675; j += 256) rb[j] = rpbp[j * 4 + head];
    if (tid < 128) {
        int lv = 0;
        if (shifted) {
            const int widx = w0g + wloc;
            const int rem = widx & ((1 << nwsh) - 1);
            const int d0 = rem >> 6, h0 = (rem >> 3) & 7, w0 = rem & 7;
            const int wd = tid >> 6, wh = (tid >> 3) & 7, ww = tid & 7;
            const int rd = (d0 < (D >> 1) - 1) ? 0 : (1 + wd);
            const int rh = (h0 < 7) ? 0 : (1 + (wh >= 4));
            const int rw = (w0 < 7) ? 0 : (1 + (ww >= 4));
            lv = rd * 9 + rh * 3 + rw;
        }
        lbl[tid] = lv;
    }
    __syncthreads();

    const int wq = tid >> 6;
    const int lane = tid & 63;
    const int l16 = lane & 15, quad = lane >> 4;
    const int myrow0 = wq * 32;

    f32x4 sc[2][8];
    #pragma unroll
    for (int mt = 0; mt < 2; mt++)
        #pragma unroll
        for (int nt = 0; nt < 8; nt++)
            sc[mt][nt] = f32x4{0.f, 0.f, 0.f, 0.f};
    #pragma unroll
    for (int kt = 0; kt < 2; kt++) {
        bf16x8 aq[2];
        #pragma unroll
        for (int mt = 0; mt < 2; mt++)
            aq[mt] = *(const bf16x8*)(Qs + (myrow0 + mt * 16 + l16) * 72 + kt * 32 + quad * 8);
        bf16x8 bk[8];
        #pragma unroll
        for (int nt = 0; nt < 8; nt++)
            bk[nt] = *(const bf16x8*)(Ks + (nt * 16 + l16) * 72 + kt * 32 + quad * 8);
        #pragma unroll
        for (int mt = 0; mt < 2; mt++)
            #pragma unroll
            for (int nt = 0; nt < 8; nt++)
                sc[mt][nt] = __builtin_amdgcn_mfma_f32_16x16x32_bf16(aq[mt], bk[nt], sc[mt][nt], 0, 0, 0);
    }

    float linv[2][4];
    #pragma unroll
    for (int mt = 0; mt < 2; mt++) {
        #pragma unroll
        for (int i = 0; i < 4; i++) {
            const int row = myrow0 + mt * 16 + quad * 4 + i;
            const int rbase = ((row >> 6) + 1) * 225 + (((row >> 3) & 7) + 7) * 15 + ((row & 7) + 7);
            const int lq = lbl[row];
            float mx = -1e30f;
            float sv[8];
            #pragma unroll
            for (int nt = 0; nt < 8; nt++) {
                const int col = nt * 16 + l16;
                float v = sc[mt][nt][i] + rb[rbase - (col >> 6) * 225 - ((col >> 3) & 7) * 15 - (col & 7)];
                if (shifted && lq != lbl[col]) v -= 100.0f;
                sv[nt] = v;
                mx = fmaxf(mx, v);
            }
            #pragma unroll
            for (int o = 1; o < 16; o <<= 1) mx = fmaxf(mx, __shfl_xor(mx, o));
            float l = 0.0f;
            #pragma unroll
            for (int nt = 0; nt < 8; nt++) {
                const float pp = __expf(sv[nt] - mx);
                sc[mt][nt][i] = pp;
                l += pp;
            }
            #pragma unroll
            for (int o = 1; o < 16; o <<= 1) l += __shfl_xor(l, o);
            linv[mt][i] = 1.0f / l;
        }
    }

    __syncthreads();
    #pragma unroll
    for (int mt = 0; mt < 2; mt++)
        #pragma unroll
        for (int nt = 0; nt < 8; nt++)
            #pragma unroll
            for (int i = 0; i < 4; i++)
                Ps[(myrow0 + mt * 16 + quad * 4 + i) * 136 + nt * 16 + l16] = f2b(sc[mt][nt][i]);

    f32x4 oc[2][4];
    #pragma unroll
    for (int mt = 0; mt < 2; mt++)
        #pragma unroll
        for (int nt = 0; nt < 4; nt++)
            oc[mt][nt] = f32x4{0.f, 0.f, 0.f, 0.f};
    #pragma unroll
    for (int kt = 0; kt < 4; kt++) {
        bf16x8 ap[2];
        #pragma unroll
        for (int mt = 0; mt < 2; mt++)
            ap[mt] = *(const bf16x8*)(Ps + (myrow0 + mt * 16 + l16) * 136 + kt * 32 + quad * 8);
        bf16x8 bv[4];
        #pragma unroll
        for (int nt = 0; nt < 4; nt++)
            bv[nt] = *(const bf16x8*)(Vt + (nt * 16 + l16) * 136 + kt * 32 + quad * 8);
        #pragma unroll
        for (int mt = 0; mt < 2; mt++)
            #pragma unroll
            for (int nt = 0; nt < 4; nt++)
                oc[mt][nt] = __builtin_amdgcn_mfma_f32_16x16x32_bf16(ap[mt], bv[nt], oc[mt][nt], 0, 0, 0);
    }

    #pragma unroll
    for (int mt = 0; mt < 2; mt++)
        #pragma unroll
        for (int nt = 0; nt < 4; nt++)
            #pragma unroll
            for (int i = 0; i < 4; i++) {
                const int row = myrow0 + mt * 16 + quad * 4 + i;
                const int col = nt * 16 + l16;
                att[(size_t)(wloc * 128 + row) * 256 + head * 64 + col] = f2b(oc[mt][nt][i] * linv[mt][i]);
            }
}

// ---------------- patch-expand LN + reorder ----------------
__global__ __launch_bounds__(256) void expand_ln_kernel(
    const float* __restrict__ sc, float* __restrict__ hout,
    const float* __restrict__ g, const float* __restrict__ bb,
    int it0, int typ)
{
    const int lane = threadIdx.x & 63;
    const int ot = blockIdx.x * 4 + (threadIdx.x >> 6);
    const int itl = ot >> 1, e = ot & 1;
    const float4 xv = *(const float4*)(sc + (size_t)itl * 512 + e * 256 + lane * 4);
    float s = xv.x + xv.y + xv.z + xv.w;
    float s2 = xv.x*xv.x + xv.y*xv.y + xv.z*xv.z + xv.w*xv.w;
    #pragma unroll
    for (int o = 32; o > 0; o >>= 1) { s += __shfl_xor(s, o); s2 += __shfl_xor(s2, o); }
    const float mu = s * 0.00390625f;
    const float var = s2 * 0.00390625f - mu * mu;
    const float rs = 1.0f / sqrtf(var + 1e-5f);
    const int c0 = lane * 4;
    const float4 gv = *(const float4*)(g + c0);
    const float4 bv = *(const float4*)(bb + c0);
    float4 y;
    y.x = (xv.x - mu) * rs * gv.x + bv.x;
    y.y = (xv.y - mu) * rs * gv.y + bv.y;
    y.z = (xv.z - mu) * rs * gv.z + bv.z;
    y.w = (xv.w - mu) * rs * gv.w + bv.w;
    const int it = it0 + itl;
    size_t otg;
    if (typ == 0) {
        const int b = it >> 14, rr = it & 16383;
        const int t = rr >> 13, v = (rr >> 12) & 1, l = rr & 4095;
        otg = (size_t)(((b * 2 + t) * 4 + v * 2 + e) * 4096 + l);
    } else {
        const int b = it >> 15, rr = it & 32767;
        const int t = rr >> 14, v2 = (rr >> 12) & 3, l = rr & 4095;
        otg = (size_t)(((b * 4 + t * 2 + e) * 4 + v2) * 4096 + l);
    }
    *(float4*)(hout + otg * 256 + c0) = y;
}

// ---------------- host ----------------
extern "C" void kernel_launch(void* const* d_in, const int* in_sizes, int n_in,
                              void* d_out, int out_size, void* d_ws, size_t ws_size,
                              hipStream_t stream)
{
    const float* x      = (const float*)d_in[0];
    const float* n1w    = (const float*)d_in[1];
    const float* n1b    = (const float*)d_in[2];
    const float* qkv_w  = (const float*)d_in[3];
    const float* qkv_b  = (const float*)d_in[4];
    const float* rpb    = (const float*)d_in[5];
    const float* proj_w = (const float*)d_in[6];
    const float* proj_b = (const float*)d_in[7];
    const float* n2w    = (const float*)d_in[8];
    const float* n2b    = (const float*)d_in[9];
    const float* mlp1_w = (const float*)d_in[10];
    const float* mlp1_b = (const float*)d_in[11];
    const float* mlp2_w = (const float*)d_in[12];
    const float* mlp2_b = (const float*)d_in[13];
    const float* expv_w = (const float*)d_in[14];
    const float* expv_nw= (const float*)d_in[15];
    const float* expv_nb= (const float*)d_in[16];
    const float* expt_w = (const float*)d_in[17];
    const float* expt_nw= (const float*)d_in[18];
    const float* expt_nb= (const float*)d_in[19];
    (void)in_sizes; (void)n_in; (void)out_size;

    if (ws_size < 352321536ULL) return;

    char* ws = (char*)d_ws;
    float* h    = (float*)ws;
    u16*  winb  = (u16*)(ws + 134217728LL);
    u16*  att   = (u16*)(ws + 134217728LL + 67108864LL);
    char* scr   = ws + 134217728LL + 2LL * 67108864LL;
    u16*  scrb  = (u16*)scr;
    float* scrf = (float*)scr;
    u16* qkvT   = (u16*)(ws + 134217728LL + 3LL * 67108864LL);
    u16* projT  = qkvT + 6 * 768 * 256;
    u16* mlp1T  = projT + 6 * 256 * 256;
    u16* mlp2T  = mlp1T + 6 * 1024 * 256;
    u16* expvT  = mlp2T + 6 * 256 * 1024;
    u16* exptT  = expvT + 512 * 256;

    wt_kernel<<<dim3(768, 6), 256, 0, stream>>>(qkv_w, qkvT, 256, 768);
    wt_kernel<<<dim3(256, 6), 256, 0, stream>>>(proj_w, projT, 256, 256);
    wt_kernel<<<dim3(1024, 6), 256, 0, stream>>>(mlp1_w, mlp1T, 256, 1024);
    wt_kernel<<<dim3(1024, 6), 256, 0, stream>>>(mlp2_w, mlp2T, 1024, 256);
    wt_kernel<<<dim3(512, 1), 256, 0, stream>>>(expv_w, expvT, 256, 512);
    wt_kernel<<<dim3(512, 1), 256, 0, stream>>>(expt_w, exptT, 256, 512);
    hipMemcpyAsync(h, x, 33554432ULL, hipMemcpyDeviceToDevice, stream);

    for (int s = 0; s < 3; s++) {
        const int D = 4 << s;
        const int dsh = 2 + s;
        const int nwsh = dsh + 5;
        const int tokens = 2 * D * 4096;
        const int nch = tokens / 32768;
        for (int j = 0; j < 2; j++) {
            const int i = 2 * s + j;
            ln_kernel<<<dim3(tokens / 4), 256, 0, stream>>>(h, winb, n1w + i * 256, n1b + i * 256, D, dsh, j, 0);
            for (int c = 0; c < nch; c++) {
                GemmP gq{};
                gq.A = winb + (size_t)c * 32768 * 256;
                gq.Bt = qkvT + (size_t)i * 768 * 256;
                gq.K = 256; gq.bias = qkv_b + i * 768; gq.outb = scrb;
                gemm_kernel<0><<<dim3(256, 6), 256, 0, stream>>>(gq);
                attn_mfma_kernel<<<dim3(256, 4), 256, 0, stream>>>(scrb, att + (size_t)c * 32768 * 256,
                                                                   rpb + i * 675 * 4, D, j, c * 256, nwsh);
            }
            GemmP gp{};
            gp.A = att; gp.Bt = projT + (size_t)i * 256 * 256; gp.K = 256;
            gp.bias = proj_b + i * 256; gp.hin = h; gp.hout = h;
            gp.D = D; gp.shifted = j; gp.nwsh = nwsh;
            gemm_kernel<1><<<dim3(tokens / 128, 2), 256, 0, stream>>>(gp);
            ln_kernel<<<dim3(tokens / 4), 256, 0, stream>>>(h, winb, n2w + i * 256, n2b + i * 256, D, dsh, 0, 1);
            for (int c = 0; c < nch; c++) {
                GemmP g1{};
                g1.A = winb + (size_t)c * 32768 * 256;
                g1.Bt = mlp1T + (size_t)i * 1024 * 256;
                g1.K = 256; g1.bias = mlp1_b + i * 1024; g1.outb = scrb;
                gemm_kernel<2><<<dim3(256, 8), 256, 0, stream>>>(g1);
                GemmP g2{};
                g2.A = scrb; g2.Bt = mlp2T + (size_t)i * 256 * 1024; g2.K = 1024;
                g2.bias = mlp2_b + i * 256; g2.hin = h; g2.row_off = c * 32768;
                g2.hout = (s == 2 && j == 1) ? (float*)d_out : h;
                gemm_kernel<3><<<dim3(256, 2), 256, 0, stream>>>(g2);
            }
        }
        if (s < 2) {
            const int ntok = tokens;
            cast_kernel<<<dim3(ntok * 64 / 256), 256, 0, stream>>>(h, winb, ntok * 64);
            const u16* eT = (s == 0) ? expvT : exptT;
            const float* eg = (s == 0) ? expv_nw : expt_nw;
            const float* eb = (s == 0) ? expv_nb : expt_nb;
            for (int c = 0; c < ntok / 32768; c++) {
                GemmP ge{};
                ge.A = winb + (size_t)c * 32768 * 256; ge.Bt = eT; ge.K = 256; ge.outf = scrf;
                gemm_kernel<4><<<dim3(256, 4), 256, 0, stream>>>(ge);
                expand_ln_kernel<<<dim3(16384), 256, 0, stream>>>(scrf, h, eg, eb, c * 32768, s);
            }
        }
    }
}

// Round 4
// 2769.231 us; speedup vs baseline: 1.1423x; 1.1423x over previous
//
#include <hip/hip_runtime.h>

typedef __bf16 bf16x8 __attribute__((ext_vector_type(8)));
typedef float f32x4 __attribute__((ext_vector_type(4)));
typedef unsigned short u16;
typedef unsigned int u32;

// ---------------- helpers ----------------
__device__ __forceinline__ u16 f2b(float f) {
    union { float f; u32 u; } v; v.f = f;
    u32 r = v.u + 0x7fffu + ((v.u >> 16) & 1u);
    return (u16)(r >> 16);
}
__device__ __forceinline__ float b2f(u16 u) {
    union { u32 u; float f; } v; v.u = ((u32)u) << 16; return v.f;
}
__device__ __forceinline__ void gl_lds16(const u16* g, u16* l) {
    __builtin_amdgcn_global_load_lds(
        (const __attribute__((address_space(1))) void*)g,
        (__attribute__((address_space(3))) void*)l, 16, 0, 0);
}

// ---------------- LN (+shift+window-partition) ----------------
__global__ __launch_bounds__(256) void ln_kernel(
    const float* __restrict__ h, u16* __restrict__ out,
    const float* __restrict__ g, const float* __restrict__ bb,
    int D, int dsh, int shifted, int mode)
{
    const int lane = threadIdx.x & 63;
    const int t = blockIdx.x * 4 + (threadIdx.x >> 6);
    const float4 xv = *(const float4*)(h + (size_t)t * 256 + lane * 4);
    float s = xv.x + xv.y + xv.z + xv.w;
    float s2 = xv.x*xv.x + xv.y*xv.y + xv.z*xv.z + xv.w*xv.w;
    #pragma unroll
    for (int o = 32; o > 0; o >>= 1) { s += __shfl_xor(s, o); s2 += __shfl_xor(s2, o); }
    const float mu = s * 0.00390625f;
    const float var = s2 * 0.00390625f - mu * mu;
    const float rs = 1.0f / sqrtf(var + 1e-5f);
    const int c0 = lane * 4;
    const float4 gv = *(const float4*)(g + c0);
    const float4 bv = *(const float4*)(bb + c0);
    ushort4 o4;
    o4.x = f2b((xv.x - mu) * rs * gv.x + bv.x);
    o4.y = f2b((xv.y - mu) * rs * gv.y + bv.y);
    o4.z = f2b((xv.z - mu) * rs * gv.z + bv.z);
    o4.w = f2b((xv.w - mu) * rs * gv.w + bv.w);
    size_t oidx;
    if (mode == 1) {
        oidx = (size_t)t * 256 + c0;
    } else {
        const int b = t >> (dsh + 12);
        const int rem = t & ((1 << (dsh + 12)) - 1);
        int d = rem >> 12;
        const int l = rem & 4095;
        int hh = l >> 6, ww = l & 63;
        if (shifted) { d = d ? d - 1 : D - 1; hh = (hh - 4) & 63; ww = (ww - 4) & 63; }
        const int widx = (b << (dsh + 5)) + ((d >> 1) << 6) + ((hh >> 3) << 3) + (ww >> 3);
        const int n = ((d & 1) << 6) + ((hh & 7) << 3) + (ww & 7);
        oidx = ((size_t)(widx * 128 + n)) * 256 + c0;
    }
    *(ushort4*)(out + oidx) = o4;
}

// ---------------- fp32 -> bf16 cast ----------------
__global__ __launch_bounds__(256) void cast_kernel(const float* __restrict__ in, u16* __restrict__ out, int n4)
{
    const int i = blockIdx.x * 256 + threadIdx.x;
    if (i >= n4) return;
    const float4 v = ((const float4*)in)[i];
    ushort4 o; o.x = f2b(v.x); o.y = f2b(v.y); o.z = f2b(v.z); o.w = f2b(v.w);
    ((ushort4*)out)[i] = o;
}

// ---------------- weight transpose+cast ----------------
__global__ __launch_bounds__(256) void wt_kernel(const float* __restrict__ src, u16* __restrict__ dst, int K, int N)
{
    const size_t base = (size_t)blockIdx.y * K * N;
    const int idx = blockIdx.x * 256 + threadIdx.x;
    const int k = idx / N, n = idx - k * N;
    dst[base + (size_t)n * K + k] = f2b(src[base + idx]);
}

// ---------------- MFMA bf16 GEMM, 128x128 tile ----------------
// Double-buffered global_load_lds (width 16) staging: prefetch panel k+1 into
// the alternate buffer before computing panel k; ONE barrier per K-iteration
// (its vmcnt(0) drain lands after the MFMAs, so prefetch flies under compute).
// XOR-swizzled 16B slots (slot_lds holds slot_glob^(row&3)) keep fragment
// ds_read_b128 conflicts ~2-way. Epilogue: two 64-row LDS-transpose chunks;
// reader thread = (row=tid>>2, float4 at (tid&3)*4 + j*16) so each store
// instruction's 4 lanes write one contiguous 64B segment (full sectors).
struct GemmP {
    const u16* A; const u16* Bt;
    int K;
    const float* bias;
    u16* outb;
    float* outf;
    const float* hin; float* hout;
    int D, shifted, nwsh, row_off;
};

template <int EPI>
__global__ __launch_bounds__(256, 2) void gemm_kernel(GemmP p)
{
    __shared__ __align__(16) char smem[33792];  // 2x(As 8K | Bs 8K); CF 64x132 f32 overlay
    float* CF = (float*)smem;

    const int tid = threadIdx.x;
    const int m0 = blockIdx.x * 128, n0 = blockIdx.y * 128;
    const int K = p.K;
    const int lane = tid & 63;
    const int wv = tid >> 6;
    const int wm = (wv & 1) * 64, wn = (wv >> 1) * 64;
    const int l16 = lane & 15, quad = lane >> 4;

    f32x4 acc[4][4];
    #pragma unroll
    for (int a = 0; a < 4; a++)
        #pragma unroll
        for (int b = 0; b < 4; b++)
            acc[a][b] = f32x4{0.f, 0.f, 0.f, 0.f};

    // staging addressing (wave wv covers rows rA0..rA0+15 and +64..+79)
    const int lrow = lane >> 2;
    const int c16s = (lane & 3) ^ (lrow & 3);
    const int rA0 = wv * 16;
    const u16* Ag = p.A + (size_t)(m0 + rA0 + lrow) * K + c16s * 8;
    const u16* Bg = p.Bt + (size_t)(n0 + rA0 + lrow) * K + c16s * 8;
    const size_t j64 = (size_t)64 * K;
    const int fslot = (quad ^ (l16 & 3)) * 8;

    // prologue: stage panel 0 into buffer 0
    {
        u16* Al = (u16*)smem + rA0 * 32;
        u16* Bl = (u16*)(smem + 8192) + rA0 * 32;
        gl_lds16(Ag, Al);
        gl_lds16(Ag + j64, Al + 64 * 32);
        gl_lds16(Bg, Bl);
        gl_lds16(Bg + j64, Bl + 64 * 32);
    }
    __syncthreads();

    int kb = 0;
    for (int k0 = 0; k0 < K; k0 += 32, kb ^= 1) {
        if (k0 + 32 < K) {  // prefetch next panel into alternate buffer
            char* nb = smem + (kb ^ 1) * 16384;
            u16* Al = (u16*)nb + rA0 * 32;
            u16* Bl = (u16*)(nb + 8192) + rA0 * 32;
            gl_lds16(Ag + k0 + 32, Al);
            gl_lds16(Ag + j64 + k0 + 32, Al + 64 * 32);
            gl_lds16(Bg + k0 + 32, Bl);
            gl_lds16(Bg + j64 + k0 + 32, Bl + 64 * 32);
        }
        const u16* As = (const u16*)(smem + kb * 16384);
        const u16* Bs = (const u16*)(smem + kb * 16384 + 8192);
        bf16x8 af[4], bfr[4];
        #pragma unroll
        for (int mt = 0; mt < 4; mt++) af[mt] = *(const bf16x8*)(As + (wm + mt * 16 + l16) * 32 + fslot);
        #pragma unroll
        for (int nt = 0; nt < 4; nt++) bfr[nt] = *(const bf16x8*)(Bs + (wn + nt * 16 + l16) * 32 + fslot);
        #pragma unroll
        for (int mt = 0; mt < 4; mt++)
            #pragma unroll
            for (int nt = 0; nt < 4; nt++)
                acc[mt][nt] = __builtin_amdgcn_mfma_f32_16x16x32_bf16(af[mt], bfr[nt], acc[mt][nt], 0, 0, 0);
        __syncthreads();  // waves done with buf kb; own prefetch drained (vmcnt0)
    }

    // ---- transposed epilogue: 2 chunks of 64 rows ----
    const int crow = tid >> 2;        // 0..63
    const int p4 = (tid & 3) * 4;     // 0,4,8,12
    #pragma unroll
    for (int c = 0; c < 2; c++) {
        if (c) __syncthreads();
        if ((wv & 1) == c) {
            #pragma unroll
            for (int mt = 0; mt < 4; mt++)
                #pragma unroll
                for (int nt = 0; nt < 4; nt++)
                    #pragma unroll
                    for (int i = 0; i < 4; i++)
                        CF[(mt * 16 + quad * 4 + i) * 132 + wn + nt * 16 + l16] = acc[mt][nt][i];
        }
        __syncthreads();
        const int rowg = m0 + c * 64 + crow;
        size_t tokbase = 0;
        if constexpr (EPI == 1) {
            const int widx = rowg >> 7, n = rowg & 127;
            const int b = widx >> p.nwsh, rem = widx & ((1 << p.nwsh) - 1);
            int dd = ((rem >> 6) << 1) + (n >> 6);
            int hh = (((rem >> 3) & 7) << 3) + ((n >> 3) & 7);
            int ww = ((rem & 7) << 3) + (n & 7);
            if (p.shifted) { dd = (dd + 1 == p.D) ? 0 : dd + 1; hh = (hh + 4) & 63; ww = (ww + 4) & 63; }
            tokbase = ((size_t)((b * p.D + dd) * 4096 + hh * 64 + ww)) * 256;
        } else if constexpr (EPI == 3) {
            tokbase = (size_t)(p.row_off + rowg) * 256;
        }
        #pragma unroll
        for (int j = 0; j < 8; j++) {
            const int colf = j * 16 + p4;
            const int colg = n0 + colf;
            const float4 t = *(const float4*)(CF + crow * 132 + colf);
            const float4 bi = (EPI <= 3) ? *(const float4*)(p.bias + colg) : float4{0.f,0.f,0.f,0.f};
            if constexpr (EPI == 0) { // qkv: +bias, q-scale, bf16 stride 768
                const float sc = (colg < 256) ? 0.125f : 1.0f;
                ushort4 pk;
                pk.x = f2b((t.x + bi.x) * sc);
                pk.y = f2b((t.y + bi.y) * sc);
                pk.z = f2b((t.z + bi.z) * sc);
                pk.w = f2b((t.w + bi.w) * sc);
                *(ushort4*)(p.outb + (size_t)rowg * 768 + colg) = pk;
            } else if constexpr (EPI == 1 || EPI == 3) { // residual fp32
                const float* hi = p.hin + tokbase + colg;
                float* ho = p.hout + tokbase + colg;
                const float4 r = *(const float4*)hi;
                float4 o;
                o.x = r.x + t.x + bi.x;
                o.y = r.y + t.y + bi.y;
                o.z = r.z + t.z + bi.z;
                o.w = r.w + t.w + bi.w;
                *(float4*)ho = o;
            } else if constexpr (EPI == 2) { // mlp1 + gelu, bf16 stride 1024
                float4 g4;
                g4.x = t.x + bi.x; g4.y = t.y + bi.y; g4.z = t.z + bi.z; g4.w = t.w + bi.w;
                ushort4 pk;
                pk.x = f2b(0.5f * g4.x * (1.0f + erff(g4.x * 0.7071067811865475f)));
                pk.y = f2b(0.5f * g4.y * (1.0f + erff(g4.y * 0.7071067811865475f)));
                pk.z = f2b(0.5f * g4.z * (1.0f + erff(g4.z * 0.7071067811865475f)));
                pk.w = f2b(0.5f * g4.w * (1.0f + erff(g4.w * 0.7071067811865475f)));
                *(ushort4*)(p.outb + (size_t)rowg * 1024 + colg) = pk;
            } else { // expand fp32 stride 512
                *(float4*)(p.outf + (size_t)rowg * 512 + colg) = t;
            }
        }
    }
}

// ---------------- MFMA attention: one block per (window, head) ----------------
__global__ __launch_bounds__(256, 2) void attn_mfma_kernel(
    const u16* __restrict__ qkv, u16* __restrict__ att,
    const float* __restrict__ rpbp, int D, int shifted, int w0g, int nwsh)
{
    __shared__ __align__(16) char smem[57856];
    u16* Qs = (u16*)smem;                       // 128*72
    u16* Ks = (u16*)(smem + 18432);
    u16* Ps = (u16*)smem;                       // 128*136 overlays Qs+Ks
    u16* Vt = (u16*)(smem + 36864);             // 64*136
    float* rb = (float*)(smem + 54272);
    int* lbl = (int*)(smem + 56972);

    const int wloc = blockIdx.x;
    const int head = blockIdx.y;
    const int tid = threadIdx.x;
    const u16* base = qkv + (size_t)wloc * 98304;

    #pragma unroll
    for (int it = 0; it < 4; it++) {
        const int id = it * 256 + tid;
        const int row = id >> 3, oct = id & 7;
        const size_t ro = (size_t)row * 768 + head * 64 + oct * 8;
        *(uint4*)(Qs + row * 72 + oct * 8) = *(const uint4*)(base + ro);
        *(uint4*)(Ks + row * 72 + oct * 8) = *(const uint4*)(base + ro + 256);
        uint4 vv = *(const uint4*)(base + ro + 512);
        const u16* vp = (const u16*)&vv;
        #pragma unroll
        for (int q = 0; q < 8; q++) Vt[(oct * 8 + q) * 136 + row] = vp[q];
    }
    for (int j = tid; j < 675; j += 256) rb[j] = rpbp[j * 4 + head];
    if (tid < 128) {
        int lv = 0;
        if (shifted) {
            const int widx = w0g + wloc;
            const int rem = widx & ((1 << nwsh) - 1);
            const int d0 = rem >> 6, h0 = (rem >> 3) & 7, w0 = rem & 7;
            const int wd = tid >> 6, wh = (tid >> 3) & 7, ww = tid & 7;
            const int rd = (d0 < (D >> 1) - 1) ? 0 : (1 + wd);
            const int rh = (h0 < 7) ? 0 : (1 + (wh >= 4));
            const int rw = (w0 < 7) ? 0 : (1 + (ww >= 4));
            lv = rd * 9 + rh * 3 + rw;
        }
        lbl[tid] = lv;
    }
    __syncthreads();

    const int wq = tid >> 6;
    const int lane = tid & 63;
    const int l16 = lane & 15, quad = lane >> 4;
    const int myrow0 = wq * 32;

    f32x4 sc[2][8];
    #pragma unroll
    for (int mt = 0; mt < 2; mt++)
        #pragma unroll
        for (int nt = 0; nt < 8; nt++)
            sc[mt][nt] = f32x4{0.f, 0.f, 0.f, 0.f};
    #pragma unroll
    for (int kt = 0; kt < 2; kt++) {
        bf16x8 aq[2];
        #pragma unroll
        for (int mt = 0; mt < 2; mt++)
            aq[mt] = *(const bf16x8*)(Qs + (myrow0 + mt * 16 + l16) * 72 + kt * 32 + quad * 8);
        bf16x8 bk[8];
        #pragma unroll
        for (int nt = 0; nt < 8; nt++)
            bk[nt] = *(const bf16x8*)(Ks + (nt * 16 + l16) * 72 + kt * 32 + quad * 8);
        #pragma unroll
        for (int mt = 0; mt < 2; mt++)
            #pragma unroll
            for (int nt = 0; nt < 8; nt++)
                sc[mt][nt] = __builtin_amdgcn_mfma_f32_16x16x32_bf16(aq[mt], bk[nt], sc[mt][nt], 0, 0, 0);
    }

    float linv[2][4];
    #pragma unroll
    for (int mt = 0; mt < 2; mt++) {
        #pragma unroll
        for (int i = 0; i < 4; i++) {
            const int row = myrow0 + mt * 16 + quad * 4 + i;
            const int rbase = ((row >> 6) + 1) * 225 + (((row >> 3) & 7) + 7) * 15 + ((row & 7) + 7);
            const int lq = lbl[row];
            float mx = -1e30f;
            float sv[8];
            #pragma unroll
            for (int nt = 0; nt < 8; nt++) {
                const int col = nt * 16 + l16;
                float v = sc[mt][nt][i] + rb[rbase - (col >> 6) * 225 - ((col >> 3) & 7) * 15 - (col & 7)];
                if (shifted && lq != lbl[col]) v -= 100.0f;
                sv[nt] = v;
                mx = fmaxf(mx, v);
            }
            #pragma unroll
            for (int o = 1; o < 16; o <<= 1) mx = fmaxf(mx, __shfl_xor(mx, o));
            float l = 0.0f;
            #pragma unroll
            for (int nt = 0; nt < 8; nt++) {
                const float pp = __expf(sv[nt] - mx);
                sc[mt][nt][i] = pp;
                l += pp;
            }
            #pragma unroll
            for (int o = 1; o < 16; o <<= 1) l += __shfl_xor(l, o);
            linv[mt][i] = 1.0f / l;
        }
    }

    __syncthreads();
    #pragma unroll
    for (int mt = 0; mt < 2; mt++)
        #pragma unroll
        for (int nt = 0; nt < 8; nt++)
            #pragma unroll
            for (int i = 0; i < 4; i++)
                Ps[(myrow0 + mt * 16 + quad * 4 + i) * 136 + nt * 16 + l16] = f2b(sc[mt][nt][i]);

    f32x4 oc[2][4];
    #pragma unroll
    for (int mt = 0; mt < 2; mt++)
        #pragma unroll
        for (int nt = 0; nt < 4; nt++)
            oc[mt][nt] = f32x4{0.f, 0.f, 0.f, 0.f};
    #pragma unroll
    for (int kt = 0; kt < 4; kt++) {
        bf16x8 ap[2];
        #pragma unroll
        for (int mt = 0; mt < 2; mt++)
            ap[mt] = *(const bf16x8*)(Ps + (myrow0 + mt * 16 + l16) * 136 + kt * 32 + quad * 8);
        bf16x8 bv[4];
        #pragma unroll
        for (int nt = 0; nt < 4; nt++)
            bv[nt] = *(const bf16x8*)(Vt + (nt * 16 + l16) * 136 + kt * 32 + quad * 8);
        #pragma unroll
        for (int mt = 0; mt < 2; mt++)
            #pragma unroll
            for (int nt = 0; nt < 4; nt++)
                oc[mt][nt] = __builtin_amdgcn_mfma_f32_16x16x32_bf16(ap[mt], bv[nt], oc[mt][nt], 0, 0, 0);
    }

    #pragma unroll
    for (int mt = 0; mt < 2; mt++)
        #pragma unroll
        for (int nt = 0; nt < 4; nt++)
            #pragma unroll
            for (int i = 0; i < 4; i++) {
                const int row = myrow0 + mt * 16 + quad * 4 + i;
                const int col = nt * 16 + l16;
                att[(size_t)(wloc * 128 + row) * 256 + head * 64 + col] = f2b(oc[mt][nt][i] * linv[mt][i]);
            }
}

// ---------------- patch-expand LN + reorder ----------------
__global__ __launch_bounds__(256) void expand_ln_kernel(
    const float* __restrict__ sc, float* __restrict__ hout,
    const float* __restrict__ g, const float* __restrict__ bb,
    int it0, int typ)
{
    const int lane = threadIdx.x & 63;
    const int ot = blockIdx.x * 4 + (threadIdx.x >> 6);
    const int itl = ot >> 1, e = ot & 1;
    const float4 xv = *(const float4*)(sc + (size_t)itl * 512 + e * 256 + lane * 4);
    float s = xv.x + xv.y + xv.z + xv.w;
    float s2 = xv.x*xv.x + xv.y*xv.y + xv.z*xv.z + xv.w*xv.w;
    #pragma unroll
    for (int o = 32; o > 0; o >>= 1) { s += __shfl_xor(s, o); s2 += __shfl_xor(s2, o); }
    const float mu = s * 0.00390625f;
    const float var = s2 * 0.00390625f - mu * mu;
    const float rs = 1.0f / sqrtf(var + 1e-5f);
    const int c0 = lane * 4;
    const float4 gv = *(const float4*)(g + c0);
    const float4 bv = *(const float4*)(bb + c0);
    float4 y;
    y.x = (xv.x - mu) * rs * gv.x + bv.x;
    y.y = (xv.y - mu) * rs * gv.y + bv.y;
    y.z = (xv.z - mu) * rs * gv.z + bv.z;
    y.w = (xv.w - mu) * rs * gv.w + bv.w;
    const int it = it0 + itl;
    size_t otg;
    if (typ == 0) {
        const int b = it >> 14, rr = it & 16383;
        const int t = rr >> 13, v = (rr >> 12) & 1, l = rr & 4095;
        otg = (size_t)(((b * 2 + t) * 4 + v * 2 + e) * 4096 + l);
    } else {
        const int b = it >> 15, rr = it & 32767;
        const int t = rr >> 14, v2 = (rr >> 12) & 3, l = rr & 4095;
        otg = (size_t)(((b * 4 + t * 2 + e) * 4 + v2) * 4096 + l);
    }
    *(float4*)(hout + otg * 256 + c0) = y;
}

// ---------------- host ----------------
extern "C" void kernel_launch(void* const* d_in, const int* in_sizes, int n_in,
                              void* d_out, int out_size, void* d_ws, size_t ws_size,
                              hipStream_t stream)
{
    const float* x      = (const float*)d_in[0];
    const float* n1w    = (const float*)d_in[1];
    const float* n1b    = (const float*)d_in[2];
    const float* qkv_w  = (const float*)d_in[3];
    const float* qkv_b  = (const float*)d_in[4];
    const float* rpb    = (const float*)d_in[5];
    const float* proj_w = (const float*)d_in[6];
    const float* proj_b = (const float*)d_in[7];
    const float* n2w    = (const float*)d_in[8];
    const float* n2b    = (const float*)d_in[9];
    const float* mlp1_w = (const float*)d_in[10];
    const float* mlp1_b = (const float*)d_in[11];
    const float* mlp2_w = (const float*)d_in[12];
    const float* mlp2_b = (const float*)d_in[13];
    const float* expv_w = (const float*)d_in[14];
    const float* expv_nw= (const float*)d_in[15];
    const float* expv_nb= (const float*)d_in[16];
    const float* expt_w = (const float*)d_in[17];
    const float* expt_nw= (const float*)d_in[18];
    const float* expt_nb= (const float*)d_in[19];
    (void)in_sizes; (void)n_in; (void)out_size;

    if (ws_size < 352321536ULL) return;

    char* ws = (char*)d_ws;
    float* h    = (float*)ws;
    u16*  winb  = (u16*)(ws + 134217728LL);
    u16*  att   = (u16*)(ws + 134217728LL + 67108864LL);
    char* scr   = ws + 134217728LL + 2LL * 67108864LL;
    u16*  scrb  = (u16*)scr;
    float* scrf = (float*)scr;
    u16* qkvT   = (u16*)(ws + 134217728LL + 3LL * 67108864LL);
    u16* projT  = qkvT + 6 * 768 * 256;
    u16* mlp1T  = projT + 6 * 256 * 256;
    u16* mlp2T  = mlp1T + 6 * 1024 * 256;
    u16* expvT  = mlp2T + 6 * 256 * 1024;
    u16* exptT  = expvT + 512 * 256;

    wt_kernel<<<dim3(768, 6), 256, 0, stream>>>(qkv_w, qkvT, 256, 768);
    wt_kernel<<<dim3(256, 6), 256, 0, stream>>>(proj_w, projT, 256, 256);
    wt_kernel<<<dim3(1024, 6), 256, 0, stream>>>(mlp1_w, mlp1T, 256, 1024);
    wt_kernel<<<dim3(1024, 6), 256, 0, stream>>>(mlp2_w, mlp2T, 1024, 256);
    wt_kernel<<<dim3(512, 1), 256, 0, stream>>>(expv_w, expvT, 256, 512);
    wt_kernel<<<dim3(512, 1), 256, 0, stream>>>(expt_w, exptT, 256, 512);
    hipMemcpyAsync(h, x, 33554432ULL, hipMemcpyDeviceToDevice, stream);

    for (int s = 0; s < 3; s++) {
        const int D = 4 << s;
        const int dsh = 2 + s;
        const int nwsh = dsh + 5;
        const int tokens = 2 * D * 4096;
        const int nch = tokens / 32768;
        for (int j = 0; j < 2; j++) {
            const int i = 2 * s + j;
            ln_kernel<<<dim3(tokens / 4), 256, 0, stream>>>(h, winb, n1w + i * 256, n1b + i * 256, D, dsh, j, 0);
            for (int c = 0; c < nch; c++) {
                GemmP gq{};
                gq.A = winb + (size_t)c * 32768 * 256;
                gq.Bt = qkvT + (size_t)i * 768 * 256;
                gq.K = 256; gq.bias = qkv_b + i * 768; gq.outb = scrb;
                gemm_kernel<0><<<dim3(256, 6), 256, 0, stream>>>(gq);
                attn_mfma_kernel<<<dim3(256, 4), 256, 0, stream>>>(scrb, att + (size_t)c * 32768 * 256,
                                                                   rpb + i * 675 * 4, D, j, c * 256, nwsh);
            }
            GemmP gp{};
            gp.A = att; gp.Bt = projT + (size_t)i * 256 * 256; gp.K = 256;
            gp.bias = proj_b + i * 256; gp.hin = h; gp.hout = h;
            gp.D = D; gp.shifted = j; gp.nwsh = nwsh;
            gemm_kernel<1><<<dim3(tokens / 128, 2), 256, 0, stream>>>(gp);
            ln_kernel<<<dim3(tokens / 4), 256, 0, stream>>>(h, winb, n2w + i * 256, n2b + i * 256, D, dsh, 0, 1);
            for (int c = 0; c < nch; c++) {
                GemmP g1{};
                g1.A = winb + (size_t)c * 32768 * 256;
                g1.Bt = mlp1T + (size_t)i * 1024 * 256;
                g1.K = 256; g1.bias = mlp1_b + i * 1024; g1.outb = scrb;
                gemm_kernel<2><<<dim3(256, 8), 256, 0, stream>>>(g1);
                GemmP g2{};
                g2.A = scrb; g2.Bt = mlp2T + (size_t)i * 256 * 1024; g2.K = 1024;
                g2.bias = mlp2_b + i * 256; g2.hin = h; g2.row_off = c * 32768;
                g2.hout = (s == 2 && j == 1) ? (float*)d_out : h;
                gemm_kernel<3><<<dim3(256, 2), 256, 0, stream>>>(g2);
            }
        }
        if (s < 2) {
            const int ntok = tokens;
            cast_kernel<<<dim3(ntok * 64 / 256), 256, 0, stream>>>(h, winb, ntok * 64);
            const u16* eT = (s == 0) ? expvT : exptT;
            const float* eg = (s == 0) ? expv_nw : expt_nw;
            const float* eb = (s == 0) ? expv_nb : expt_nb;
            for (int c = 0; c < ntok / 32768; c++) {
                GemmP ge{};
                ge.A = winb + (size_t)c * 32768 * 256; ge.Bt = eT; ge.K = 256; ge.outf = scrf;
                gemm_kernel<4><<<dim3(256, 4), 256, 0, stream>>>(ge);
                expand_ln_kernel<<<dim3(16384), 256, 0, stream>>>(scrf, h, eg, eb, c * 32768, s);
            }
        }
    }
}